// Round 6
// baseline (209.168 us; speedup 1.0000x reference)
//
#include <hip/hip_runtime.h>

// ------- MFMA fp16 LSTM, skewed-layer pipeline, ILP-staged gate math -------
// Phase p computes layer1(t=p) AND layer0(t=p+1) between barriers (29 barriers).
// This round: __launch_bounds__(512,2) (VGPR cap 256) + breadth-first gate math
// (all exps, then all adds, then all rcps across 4 tiles) + branch-free main loop
// (prologue/final phases peeled). Formulas identical to round 5 -> same absmax.
//
// GEMM: C[m=gate(256)][n=batch(32)] = W[m][k] * data[k][n], gate rows permuted
// row'=4*unit+gate so a lane's 4 C-regs = (i,f,g,o) of one unit; c-state in VGPRs.
// Block = 512 thr (8 waves), wave w owns m-tiles {2w,2w+1} x n-tiles {0,1}.
// A (weights) gathered once per block from global fp32 (L2-resident).
// bias0 folded as k=28 constant-1 column; bias1 pre-added into acc init.
// B in LDS frag-linear layout: lane reads 16B at lane*16, conflict-free b128.
// Planes: h0(t) in h0p[t&1], h1(t) in h1p[t&1], x(t) in xb[t&1].

typedef _Float16 half8 __attribute__((ext_vector_type(8)));
typedef float floatx4 __attribute__((ext_vector_type(4)));

// Breadth-first 4-tile gate batch: acc -> (c update, h write). Same math as
// sigf/tanhf2 of rounds 3-5, restaged for trans-pipe ILP (16 indep exps, etc).
__device__ __forceinline__ void gate_batch4(const floatx4 (&acc)[2][2], float (&c)[4],
                                            _Float16* __restrict__ plane,
                                            const int (&hwr)[2][2]) {
    float ei[4], ef[4], eg[4], eo[4];
    #pragma unroll
    for (int tt = 0; tt < 4; ++tt) {
        floatx4 a = acc[tt >> 1][tt & 1];
        ei[tt] = __expf(-a[0]);
        ef[tt] = __expf(-a[1]);
        eg[tt] = __expf(2.0f * a[2]);
        eo[tt] = __expf(-a[3]);
    }
    float ri[4], rf[4], rg[4], ro[4];
    #pragma unroll
    for (int tt = 0; tt < 4; ++tt) {
        ri[tt] = __builtin_amdgcn_rcpf(1.0f + ei[tt]);
        rf[tt] = __builtin_amdgcn_rcpf(1.0f + ef[tt]);
        rg[tt] = __builtin_amdgcn_rcpf(1.0f + eg[tt]);
        ro[tt] = __builtin_amdgcn_rcpf(1.0f + eo[tt]);
    }
    float ec[4];
    #pragma unroll
    for (int tt = 0; tt < 4; ++tt) {
        float tg = 1.0f - 2.0f * rg[tt];
        float cn = rf[tt] * c[tt] + ri[tt] * tg;
        c[tt] = cn;
        ec[tt] = __expf(2.0f * cn);
    }
    #pragma unroll
    for (int tt = 0; tt < 4; ++tt) {
        float tc = 1.0f - 2.0f * __builtin_amdgcn_rcpf(ec[tt] + 1.0f);
        plane[hwr[tt >> 1][tt & 1]] = (_Float16)(ro[tt] * tc);
    }
}

__launch_bounds__(512, 2)
__global__ void lstm_mfma(const float* __restrict__ x,
                          const float* __restrict__ Wih0, const float* __restrict__ Whh0,
                          const float* __restrict__ bih0, const float* __restrict__ bhh0,
                          const float* __restrict__ Wih1, const float* __restrict__ Whh1,
                          const float* __restrict__ bih1, const float* __restrict__ bhh1,
                          const float* __restrict__ Wlin, const float* __restrict__ blin,
                          float* __restrict__ out) {
    __shared__ __align__(16) _Float16 h0p[2][2048];  // [parity][(nt*2+kt)*512 + lane*8 + j]
    __shared__ __align__(16) _Float16 h1p[2][2048];
    __shared__ __align__(16) _Float16 xb[2][1024];   // [parity][nt*512 + lane*8 + j]
    __shared__ float wlin_s[640];
    __shared__ float blin_s[10];

    const int lane = threadIdx.x;
    const int w    = threadIdx.y;          // 0..7
    const int tid  = w * 64 + lane;        // 0..511
    const int quad = lane >> 4;
    const int col  = lane & 15;

    // ---- gather A fragments from global fp32 weights (one-time; L2-resident) ----
    half8 A0[2][3], A1[2][4];
    #pragma unroll
    for (int im = 0; im < 2; ++im) {
        int mt = 2 * w + im;
        int m  = mt * 16 + col;
        int u  = m >> 2, g = m & 3;
        int row = g * 64 + u;                       // original weight row
        #pragma unroll
        for (int kt = 0; kt < 3; ++kt) {
            half8 r;
            #pragma unroll
            for (int j = 0; j < 8; ++j) {
                int k = kt * 32 + quad * 8 + j;
                float v;
                if (k < 28)       v = Wih0[row * 28 + k];
                else if (k == 28) v = bih0[row] + bhh0[row];
                else if (k < 32)  v = 0.f;
                else              v = Whh0[row * 64 + (k - 32)];
                r[j] = (_Float16)v;
            }
            A0[im][kt] = r;
        }
        #pragma unroll
        for (int kt = 0; kt < 4; ++kt) {
            half8 r;
            #pragma unroll
            for (int j = 0; j < 8; ++j) {
                int k = kt * 32 + quad * 8 + j;
                float v = (k < 64) ? Wih1[row * 64 + k] : Whh1[row * 64 + (k - 64)];
                r[j] = (_Float16)v;
            }
            A1[im][kt] = r;
        }
    }
    floatx4 bias1[2];
    #pragma unroll
    for (int im = 0; im < 2; ++im) {
        int u = (2 * w + im) * 4 + quad;
        #pragma unroll
        for (int r = 0; r < 4; ++r) bias1[im][r] = bih1[r * 64 + u] + bhh1[r * 64 + u];
    }

    // ---- t-invariant LDS offsets (halves) ----
    int xrd[2], hrd[2][2], hwr[2][2];
    #pragma unroll
    for (int in = 0; in < 2; ++in) {
        xrd[in] = in * 512 + lane * 8;
        #pragma unroll
        for (int kt = 0; kt < 2; ++kt) hrd[kt][in] = (in * 2 + kt) * 512 + lane * 8;
        #pragma unroll
        for (int im = 0; im < 2; ++im) {
            int u = (2 * w + im) * 4 + quad;
            hwr[im][in] = (in * 2 + (u >> 5)) * 512 + (((u >> 3) & 3) * 16 + col) * 8 + (u & 7);
        }
    }

    // ---- x prefetch: slot s covers b=(tid>>5)+16s, i=tid&31 ----
    const int xi = tid & 31;
    const bool xvalid = xi < 28;
    const float* xg[2];
    int xstg[2];
    #pragma unroll
    for (int s = 0; s < 2; ++s) {
        int b = (tid >> 5) + s * 16;
        xg[s]   = x + (blockIdx.x * 32 + b) * 784 + xi;
        xstg[s] = (b >> 4) * 512 + ((xi >> 3) * 16 + (b & 15)) * 8 + (xi & 7);
    }

    // ---- init: zero h0(-1)=h0p[1], h1(-1)=h1p[1]; stage x(0) into xb[0] ----
    {
        int* z0 = (int*)&h0p[1][0];
        int* z1 = (int*)&h1p[1][0];
        #pragma unroll
        for (int i = tid; i < 1024; i += 512) { z0[i] = 0; z1[i] = 0; }
        #pragma unroll
        for (int s = 0; s < 2; ++s) {
            float xv = xvalid ? xg[s][0] : 0.f;
            xb[0][xstg[s]] = (xi == 28) ? (_Float16)1.0f : (_Float16)xv;
        }
    }
    __syncthreads();

    float c0[4] = {0.f, 0.f, 0.f, 0.f};
    float c1[4] = {0.f, 0.f, 0.f, 0.f};

    // ======== prologue phase (p = -1): layer0(t=0) only ========
    {
        float xn[2] = {0.f, 0.f};
        #pragma unroll
        for (int s = 0; s < 2; ++s)
            if (xvalid) xn[s] = xg[s][28];          // x(1)

        floatx4 acc0[2][2];
        #pragma unroll
        for (int im = 0; im < 2; ++im)
            #pragma unroll
            for (int in = 0; in < 2; ++in)
                acc0[im][in] = (floatx4){0.f, 0.f, 0.f, 0.f};
        #pragma unroll
        for (int in = 0; in < 2; ++in) {
            half8 bf = *(const half8*)&xb[0][xrd[in]];
            #pragma unroll
            for (int im = 0; im < 2; ++im)
                acc0[im][in] = __builtin_amdgcn_mfma_f32_16x16x32_f16(A0[im][0], bf, acc0[im][in], 0, 0, 0);
        }
        #pragma unroll
        for (int kt = 0; kt < 2; ++kt) {
            #pragma unroll
            for (int in = 0; in < 2; ++in) {
                half8 bf = *(const half8*)&h0p[1][hrd[kt][in]];   // zeros
                #pragma unroll
                for (int im = 0; im < 2; ++im)
                    acc0[im][in] = __builtin_amdgcn_mfma_f32_16x16x32_f16(A0[im][kt + 1], bf, acc0[im][in], 0, 0, 0);
            }
        }
        gate_batch4(acc0, c0, &h0p[0][0], hwr);     // h0(0) -> plane 0
        #pragma unroll
        for (int s = 0; s < 2; ++s)                 // stage x(1) -> plane 1
            xb[1][xstg[s]] = (xi == 28) ? (_Float16)1.0f : (_Float16)xn[s];
        __syncthreads();
    }

    // ======== main phases p = 0..26: layer1(p) + layer0(p+1), branch-free ========
    for (int p = 0; p < 27; ++p) {
        const int pr  = p & 1;
        const int pr1 = pr ^ 1;
        const _Float16* h0r = &h0p[pr][0];          // h0(p)
        _Float16*       h0w = &h0p[pr1][0];         // h0(p+1)
        const _Float16* h1r = &h1p[pr1][0];         // h1(p-1)
        _Float16*       h1w = &h1p[pr][0];          // h1(p)
        const _Float16* xr  = &xb[pr1][0];          // x(p+1)
        _Float16*       xw  = &xb[pr][0];           // x(p+2) stage

        // global prefetch x(p+2) (clamped at p=26: re-reads x(27), harmless)
        const int xoff = (p < 26 ? p + 2 : 27) * 28;
        float xn[2] = {0.f, 0.f};
        #pragma unroll
        for (int s = 0; s < 2; ++s)
            if (xvalid) xn[s] = xg[s][xoff];

        // ---- B-fragment loads ----
        half8 bh0[2][2], bh1[2][2], bx[2];
        #pragma unroll
        for (int in = 0; in < 2; ++in) {
            bx[in] = *(const half8*)&xr[xrd[in]];
            #pragma unroll
            for (int kt = 0; kt < 2; ++kt) {
                bh0[kt][in] = *(const half8*)&h0r[hrd[kt][in]];
                bh1[kt][in] = *(const half8*)&h1r[hrd[kt][in]];
            }
        }

        // ---- all 28 MFMAs (both layers, independent) ----
        floatx4 acc0[2][2], acc1[2][2];
        #pragma unroll
        for (int im = 0; im < 2; ++im)
            #pragma unroll
            for (int in = 0; in < 2; ++in) {
                acc0[im][in] = (floatx4){0.f, 0.f, 0.f, 0.f};
                acc1[im][in] = bias1[im];
            }
        #pragma unroll
        for (int in = 0; in < 2; ++in)
            #pragma unroll
            for (int im = 0; im < 2; ++im)
                acc0[im][in] = __builtin_amdgcn_mfma_f32_16x16x32_f16(A0[im][0], bx[in], acc0[im][in], 0, 0, 0);
        #pragma unroll
        for (int kt = 0; kt < 2; ++kt)
            #pragma unroll
            for (int in = 0; in < 2; ++in)
                #pragma unroll
                for (int im = 0; im < 2; ++im) {
                    acc0[im][in] = __builtin_amdgcn_mfma_f32_16x16x32_f16(A0[im][kt + 1], bh0[kt][in], acc0[im][in], 0, 0, 0);
                    acc1[im][in] = __builtin_amdgcn_mfma_f32_16x16x32_f16(A1[im][kt],     bh0[kt][in], acc1[im][in], 0, 0, 0);
                    acc1[im][in] = __builtin_amdgcn_mfma_f32_16x16x32_f16(A1[im][kt + 2], bh1[kt][in], acc1[im][in], 0, 0, 0);
                }

        // ---- gates (breadth-first), writes, x stage ----
        gate_batch4(acc0, c0, h0w, hwr);            // h0(p+1)
        gate_batch4(acc1, c1, h1w, hwr);            // h1(p)
        #pragma unroll
        for (int s = 0; s < 2; ++s)
            xw[xstg[s]] = (xi == 28) ? (_Float16)1.0f : (_Float16)xn[s];
        __syncthreads();
    }

    // ======== final phase (p = 27): layer1(t=27) only ========
    {
        floatx4 acc1[2][2];
        #pragma unroll
        for (int im = 0; im < 2; ++im)
            #pragma unroll
            for (int in = 0; in < 2; ++in)
                acc1[im][in] = bias1[im];
        #pragma unroll
        for (int kt = 0; kt < 2; ++kt) {
            #pragma unroll
            for (int in = 0; in < 2; ++in) {
                half8 b0 = *(const half8*)&h0p[1][hrd[kt][in]];   // h0(27)
                half8 b1 = *(const half8*)&h1p[0][hrd[kt][in]];   // h1(26)
                #pragma unroll
                for (int im = 0; im < 2; ++im) {
                    acc1[im][in] = __builtin_amdgcn_mfma_f32_16x16x32_f16(A1[im][kt],     b0, acc1[im][in], 0, 0, 0);
                    acc1[im][in] = __builtin_amdgcn_mfma_f32_16x16x32_f16(A1[im][kt + 2], b1, acc1[im][in], 0, 0, 0);
                }
            }
        }
        gate_batch4(acc1, c1, &h1p[1][0], hwr);     // h1(27) -> plane 1
        __syncthreads();
    }

    // ---- epilogue: out = h1(27) @ Wlin^T + blin   (h1(27) in h1p[1]) ----
    #pragma unroll
    for (int i = tid; i < 640; i += 512) wlin_s[i] = Wlin[i];
    if (tid < 10) blin_s[tid] = blin[tid];
    __syncthreads();
    if (tid < 320) {
        int b = tid / 10, o = tid - b * 10;
        float a = blin_s[o];
        #pragma unroll 8
        for (int u = 0; u < 64; ++u) {
            float hv = (float)h1p[1][((b >> 4) * 2 + (u >> 5)) * 512 + (((u >> 3) & 3) * 16 + (b & 15)) * 8 + (u & 7)];
            a += wlin_s[o * 64 + u] * hv;
        }
        out[(blockIdx.x * 32 + b) * 10 + o] = a;
    }
}

extern "C" void kernel_launch(void* const* d_in, const int* in_sizes, int n_in,
                              void* d_out, int out_size, void* d_ws, size_t ws_size,
                              hipStream_t stream) {
    const float* x    = (const float*)d_in[0];
    const float* Wih0 = (const float*)d_in[1];
    const float* Whh0 = (const float*)d_in[2];
    const float* bih0 = (const float*)d_in[3];
    const float* bhh0 = (const float*)d_in[4];
    const float* Wih1 = (const float*)d_in[5];
    const float* Whh1 = (const float*)d_in[6];
    const float* bih1 = (const float*)d_in[7];
    const float* bhh1 = (const float*)d_in[8];
    const float* Wlin = (const float*)d_in[9];
    const float* blin = (const float*)d_in[10];
    float* out = (float*)d_out;

    lstm_mfma<<<512, dim3(64, 8), 0, stream>>>(x, Wih0, Whh0, bih0, bhh0,
                                               Wih1, Whh1, bih1, bhh1, Wlin, blin, out);
}